// Round 1
// baseline (998.016 us; speedup 1.0000x reference)
//
#include <hip/hip_runtime.h>
#include <hip/hip_bf16.h>
#include <math.h>

constexpr int NB = 64;     // batch
constexpr int NS = 2048;   // tokens
constexpr int ND = 1024;   // model dim
constexpr int NE = 32;     // experts
constexpr int NH = 4096;   // hidden
constexpr int NK = 8;      // top-k tokens per expert

// ---------------------------------------------------------------------------
// Kernel 1: gating GEMM  logitsT[b][e][s] = x[b,s,:] . gate_w[e,:] + gate_b[e]
// fp64 accumulation (top-k selection must match reference's fp arithmetic
// closely; fp32 sequential accumulation error ~2.5e-5 risks boundary flips).
// Block: 64 tokens x 32 experts, 256 threads, K staged in LDS (transposed).
// ---------------------------------------------------------------------------
__global__ __launch_bounds__(256) void k_gate(const float* __restrict__ x,
                                              const float* __restrict__ gw,
                                              const float* __restrict__ gb,
                                              float* __restrict__ logitsT) {
  const int b  = blockIdx.y;
  const int s0 = blockIdx.x * 64;
  const int t  = threadIdx.x;
  __shared__ float xT[128][64];   // [k][m]
  __shared__ float gwT[128][32];  // [k][e]
  double acc[4][2] = {};
  const int tm = t & 15;          // m-tile: 4 consecutive tokens
  const int te = t >> 4;          // e-tile: 2 consecutive experts
  const int lm = t & 63, lkq = t >> 6;   // x staging
  const int le = t & 31, loct = t >> 5;  // gw staging

  for (int kc = 0; kc < 8; ++kc) {
    const int k0 = kc * 128;
#pragma unroll
    for (int j = 0; j < 8; ++j) {
      int k = lkq * 32 + j * 4;
      float4 v = *(const float4*)&x[((size_t)b * NS + s0 + lm) * ND + k0 + k];
      xT[k + 0][lm] = v.x; xT[k + 1][lm] = v.y;
      xT[k + 2][lm] = v.z; xT[k + 3][lm] = v.w;
    }
#pragma unroll
    for (int j = 0; j < 4; ++j) {
      int k = loct * 16 + j * 4;
      float4 v = *(const float4*)&gw[(size_t)le * ND + k0 + k];
      gwT[k + 0][le] = v.x; gwT[k + 1][le] = v.y;
      gwT[k + 2][le] = v.z; gwT[k + 3][le] = v.w;
    }
    __syncthreads();
#pragma unroll 4
    for (int k = 0; k < 128; ++k) {
      float4 a = *(const float4*)&xT[k][tm * 4];
      double w0 = (double)gwT[k][te * 2];
      double w1 = (double)gwT[k][te * 2 + 1];
      acc[0][0] += (double)a.x * w0; acc[1][0] += (double)a.y * w0;
      acc[2][0] += (double)a.z * w0; acc[3][0] += (double)a.w * w0;
      acc[0][1] += (double)a.x * w1; acc[1][1] += (double)a.y * w1;
      acc[2][1] += (double)a.z * w1; acc[3][1] += (double)a.w * w1;
    }
    __syncthreads();
  }
  const int e0 = te * 2;
#pragma unroll
  for (int ei = 0; ei < 2; ++ei) {
    double bias = (double)gb[e0 + ei];
    float4 r;
    r.x = (float)(acc[0][ei] + bias);
    r.y = (float)(acc[1][ei] + bias);
    r.z = (float)(acc[2][ei] + bias);
    r.w = (float)(acc[3][ei] + bias);
    *(float4*)&logitsT[((size_t)b * NE + e0 + ei) * NS + s0 + tm * 4] = r;
  }
}

// ---------------------------------------------------------------------------
// Kernel 2: per (b,e): softmax denominator over S tokens + top-8 by logit
// (monotone-equivalent to top-8 by softmax prob). Ties -> lower index,
// matching jax.lax.top_k. One wave per (b,e).
// ---------------------------------------------------------------------------
__global__ __launch_bounds__(64) void k_topk(const float* __restrict__ logitsT,
                                             float* __restrict__ tval,
                                             int* __restrict__ tidx) {
  const int be = blockIdx.x;
  const float* row = logitsT + (size_t)be * NS;
  const int lane = threadIdx.x;

  float p8[8]; int i8[8];
#pragma unroll
  for (int j = 0; j < 8; ++j) { p8[j] = -INFINITY; i8[j] = 0x7fffffff; }
  float mx = -INFINITY;
  for (int s = lane; s < NS; s += 64) {
    float l = row[s];
    mx = fmaxf(mx, l);
    if (l > p8[0] || (l == p8[0] && s < i8[0])) {
      int pos = 0;
#pragma unroll
      for (int j = 1; j < 8; ++j) {
        if (l > p8[j] || (l == p8[j] && s < i8[j])) {
          p8[j - 1] = p8[j]; i8[j - 1] = i8[j]; pos = j;
        } else break;
      }
      p8[pos] = l; i8[pos] = s;
    }
  }
#pragma unroll
  for (int off = 32; off; off >>= 1) mx = fmaxf(mx, __shfl_xor(mx, off));
  double sum = 0.0;
  for (int s = lane; s < NS; s += 64) sum += (double)expf(row[s] - mx);
#pragma unroll
  for (int off = 32; off; off >>= 1) sum += __shfl_xor(sum, off);
  const double inv = 1.0 / sum;

  int ptr = 7;
  for (int r = 0; r < 8; ++r) {
    float bp = (ptr >= 0) ? p8[ptr] : -INFINITY;
    int   bi = (ptr >= 0) ? i8[ptr] : 0x7fffffff;
    int   bl = lane;
#pragma unroll
    for (int off = 1; off < 64; off <<= 1) {
      float op = __shfl_xor(bp, off);
      int   oi = __shfl_xor(bi, off);
      int   ol = __shfl_xor(bl, off);
      if (op > bp || (op == bp && oi < bi)) { bp = op; bi = oi; bl = ol; }
    }
    if (lane == 0) {
      tval[be * 8 + r] = (float)((double)expf(bp - mx) * inv);
      tidx[be * 8 + r] = bi;
    }
    if (lane == bl) ptr--;
  }
}

// ---------------------------------------------------------------------------
// Kernel 3: mux/merge  merged[b][e][d] = sum_k val_k * x[b][idx_k][d]
// ---------------------------------------------------------------------------
__global__ __launch_bounds__(256) void k_merge(const float* __restrict__ x,
                                               const float* __restrict__ tval,
                                               const int* __restrict__ tidx,
                                               float* __restrict__ merged) {
  const int be = blockIdx.x;
  const int b  = be >> 5;
  const int t  = threadIdx.x;
  float4 acc = {0.f, 0.f, 0.f, 0.f};
#pragma unroll
  for (int k = 0; k < 8; ++k) {
    float v = tval[be * 8 + k];
    int   s = tidx[be * 8 + k];
    float4 xv = *(const float4*)&x[((size_t)b * NS + s) * ND + t * 4];
    acc.x += v * xv.x; acc.y += v * xv.y; acc.z += v * xv.z; acc.w += v * xv.w;
  }
  *(float4*)&merged[(size_t)be * ND + t * 4] = acc;
}

// ---------------------------------------------------------------------------
// Kernels 4/5: per-expert FFN GEMM.  M=64 (batches), K, N templated.
// A rows are [m*NE+e] of length K; W is [E][K+1][N] (last row = bias).
// Block: full M x 64 N-cols; Kc=64 staged in LDS (A transposed to [k][m]).
// Thread tile 4x4, fp32 vector FMA.
// ---------------------------------------------------------------------------
__device__ __forceinline__ float gelu_exact(float v) {
  return 0.5f * v * (1.0f + erff(v * 0.70710678118654752440f));
}

template <int K, int N, bool GELU>
__global__ __launch_bounds__(256) void k_ffn(const float* __restrict__ A,
                                             const float* __restrict__ W,
                                             float* __restrict__ Out) {
  const int e  = blockIdx.y;
  const int n0 = blockIdx.x * 64;
  const int t  = threadIdx.x;
  __shared__ float AT[64][64];  // [k][m]
  __shared__ float Wl[64][64];  // [k][n]
  float acc[4][4] = {};
  const int tm = t & 15, tn = t >> 4;
  const int lm = t & 63, lkq = t >> 6;
  const float* Wbase = W + (size_t)e * (K + 1) * N;

  for (int kc = 0; kc < K / 64; ++kc) {
    const int k0 = kc * 64;
#pragma unroll
    for (int j = 0; j < 4; ++j) {
      int k = lkq * 16 + j * 4;
      float4 v = *(const float4*)&A[((size_t)lm * NE + e) * K + k0 + k];
      AT[k + 0][lm] = v.x; AT[k + 1][lm] = v.y;
      AT[k + 2][lm] = v.z; AT[k + 3][lm] = v.w;
    }
#pragma unroll
    for (int jj = 0; jj < 4; ++jj) {
      int r = jj * 16 + (t >> 4);
      int c = (t & 15) * 4;
      float4 v = *(const float4*)&Wbase[(size_t)(k0 + r) * N + n0 + c];
      *(float4*)&Wl[r][c] = v;
    }
    __syncthreads();
#pragma unroll 8
    for (int k = 0; k < 64; ++k) {
      float4 a = *(const float4*)&AT[k][tm * 4];
      float4 w = *(const float4*)&Wl[k][tn * 4];
      acc[0][0] += a.x * w.x; acc[0][1] += a.x * w.y; acc[0][2] += a.x * w.z; acc[0][3] += a.x * w.w;
      acc[1][0] += a.y * w.x; acc[1][1] += a.y * w.y; acc[1][2] += a.y * w.z; acc[1][3] += a.y * w.w;
      acc[2][0] += a.z * w.x; acc[2][1] += a.z * w.y; acc[2][2] += a.z * w.z; acc[2][3] += a.z * w.w;
      acc[3][0] += a.w * w.x; acc[3][1] += a.w * w.y; acc[3][2] += a.w * w.z; acc[3][3] += a.w * w.w;
    }
    __syncthreads();
  }
  // bias row (index K), then optional exact GELU, then store
  float4 bw = *(const float4*)&Wbase[(size_t)K * N + n0 + tn * 4];
#pragma unroll
  for (int mi = 0; mi < 4; ++mi) {
    float4 r;
    r.x = acc[mi][0] + bw.x;
    r.y = acc[mi][1] + bw.y;
    r.z = acc[mi][2] + bw.z;
    r.w = acc[mi][3] + bw.w;
    if (GELU) {
      r.x = gelu_exact(r.x); r.y = gelu_exact(r.y);
      r.z = gelu_exact(r.z); r.w = gelu_exact(r.w);
    }
    const int m = tm * 4 + mi;
    *(float4*)&Out[((size_t)m * NE + e) * N + n0 + tn * 4] = r;
  }
}

// ---------------------------------------------------------------------------
// Kernel 6: demux/scatter. One block per (b, token). The 256 threads each own
// one (e,k) slot; ballot which slots picked this token; accumulate those
// experts' outputs (fixed slot order -> deterministic, no atomics). Tokens
// picked by nobody write exact zeros (doubles as the output clear).
// ---------------------------------------------------------------------------
__global__ __launch_bounds__(256) void k_scatter(const float* __restrict__ Obuf,
                                                 const float* __restrict__ tval,
                                                 const int* __restrict__ tidx,
                                                 float* __restrict__ out) {
  const int s = blockIdx.x;
  const int b = blockIdx.y;
  const int t = threadIdx.x;
  __shared__ unsigned long long masks[4];

  const int myIdx = tidx[b * 256 + t];  // slot t = e*8 + k
  unsigned long long m = __ballot(myIdx == s);
  if ((t & 63) == 0) masks[t >> 6] = m;
  __syncthreads();

  float4 acc = {0.f, 0.f, 0.f, 0.f};
#pragma unroll
  for (int w = 0; w < 4; ++w) {
    unsigned long long mm = masks[w];
    while (mm) {
      int bit = __ffsll(mm) - 1;
      mm &= mm - 1;
      int r = w * 64 + bit;           // r = e*8 + k
      float v = tval[b * 256 + r];
      const float4 ov = *(const float4*)&Obuf[((size_t)b * NE + (r >> 3)) * ND + t * 4];
      acc.x += v * ov.x; acc.y += v * ov.y; acc.z += v * ov.z; acc.w += v * ov.w;
    }
  }
  *(float4*)&out[((size_t)b * NS + s) * ND + t * 4] = acc;
}

// ---------------------------------------------------------------------------
extern "C" void kernel_launch(void* const* d_in, const int* in_sizes, int n_in,
                              void* d_out, int out_size, void* d_ws, size_t ws_size,
                              hipStream_t stream) {
  const float* x  = (const float*)d_in[0];
  const float* gw = (const float*)d_in[1];
  const float* gb = (const float*)d_in[2];
  const float* w1 = (const float*)d_in[3];
  const float* w2 = (const float*)d_in[4];
  float* out = (float*)d_out;

  // workspace layout (floats): ~67 MB total
  float* ws      = (float*)d_ws;
  float* logitsT = ws;                                   // [B][E][S]
  float* tval    = logitsT + (size_t)NB * NE * NS;       // [B][E][8]
  int*   tidx    = (int*)(tval + (size_t)NB * NE * NK);  // [B][E][8]
  float* merged  = (float*)(tidx + (size_t)NB * NE * NK);// [B][E][D]
  float* Hbuf    = merged + (size_t)NB * NE * ND;        // [B][E][H]
  float* Obuf    = Hbuf + (size_t)NB * NE * NH;          // [B][E][D]

  k_gate<<<dim3(NS / 64, NB), 256, 0, stream>>>(x, gw, gb, logitsT);
  k_topk<<<NB * NE, 64, 0, stream>>>(logitsT, tval, tidx);
  k_merge<<<NB * NE, 256, 0, stream>>>(x, tval, tidx, merged);
  k_ffn<ND, NH, true><<<dim3(NH / 64, NE), 256, 0, stream>>>(merged, w1, Hbuf);
  k_ffn<NH, ND, false><<<dim3(ND / 64, NE), 256, 0, stream>>>(Hbuf, w2, Obuf);
  k_scatter<<<dim3(NS, NB), 256, 0, stream>>>(Obuf, tval, tidx, out);
}

// Round 2
// 731.847 us; speedup vs baseline: 1.3637x; 1.3637x over previous
//
#include <hip/hip_runtime.h>
#include <hip/hip_bf16.h>
#include <math.h>

constexpr int NB = 64;     // batch
constexpr int NS = 2048;   // tokens
constexpr int ND = 1024;   // model dim
constexpr int NE = 32;     // experts
constexpr int NH = 4096;   // hidden
constexpr int NK = 8;      // top-k tokens per expert

typedef short bf16x8 __attribute__((ext_vector_type(8)));
typedef float f32x4  __attribute__((ext_vector_type(4)));

// ---------------------------------------------------------------------------
// fp32 -> (hi, lo) bf16 split. hi = RNE(v); lo = RNE(v - hi). Combined
// mantissa ~16 bits => rel error ~2^-16 per element, safely below the
// 1.28e-4 absmax threshold after two GEMMs.
// ---------------------------------------------------------------------------
__device__ __forceinline__ unsigned short f2bf_rne(float v) {
  unsigned u = __builtin_bit_cast(unsigned, v);
  u += 0x7fffu + ((u >> 16) & 1u);
  return (unsigned short)(u >> 16);
}
__device__ __forceinline__ void split_bf16(float v, unsigned short& h, unsigned short& l) {
  h = f2bf_rne(v);
  float fh = __builtin_bit_cast(float, (unsigned)h << 16);
  l = f2bf_rne(v - fh);
}

// ---------------------------------------------------------------------------
// Kernel 1: gating GEMM  logitsT[b][e][s] = x[b,s,:] . gate_w[e,:] + gate_b[e]
// fp64 accumulation: top-k selection must match the fp64 numpy reference's
// ordering; fp32/bf16 logit error (~1e-5..1e-6) risks boundary flips.
// ---------------------------------------------------------------------------
__global__ __launch_bounds__(256) void k_gate(const float* __restrict__ x,
                                              const float* __restrict__ gw,
                                              const float* __restrict__ gb,
                                              float* __restrict__ logitsT) {
  const int b  = blockIdx.y;
  const int s0 = blockIdx.x * 64;
  const int t  = threadIdx.x;
  __shared__ float xT[128][64];   // [k][m]
  __shared__ float gwT[128][32];  // [k][e]
  double acc[4][2] = {};
  const int tm = t & 15;
  const int te = t >> 4;
  const int lm = t & 63, lkq = t >> 6;
  const int le = t & 31, loct = t >> 5;

  for (int kc = 0; kc < 8; ++kc) {
    const int k0 = kc * 128;
#pragma unroll
    for (int j = 0; j < 8; ++j) {
      int k = lkq * 32 + j * 4;
      float4 v = *(const float4*)&x[((size_t)b * NS + s0 + lm) * ND + k0 + k];
      xT[k + 0][lm] = v.x; xT[k + 1][lm] = v.y;
      xT[k + 2][lm] = v.z; xT[k + 3][lm] = v.w;
    }
#pragma unroll
    for (int j = 0; j < 4; ++j) {
      int k = loct * 16 + j * 4;
      float4 v = *(const float4*)&gw[(size_t)le * ND + k0 + k];
      gwT[k + 0][le] = v.x; gwT[k + 1][le] = v.y;
      gwT[k + 2][le] = v.z; gwT[k + 3][le] = v.w;
    }
    __syncthreads();
#pragma unroll 4
    for (int k = 0; k < 128; ++k) {
      float4 a = *(const float4*)&xT[k][tm * 4];
      double w0 = (double)gwT[k][te * 2];
      double w1 = (double)gwT[k][te * 2 + 1];
      acc[0][0] += (double)a.x * w0; acc[1][0] += (double)a.y * w0;
      acc[2][0] += (double)a.z * w0; acc[3][0] += (double)a.w * w0;
      acc[0][1] += (double)a.x * w1; acc[1][1] += (double)a.y * w1;
      acc[2][1] += (double)a.z * w1; acc[3][1] += (double)a.w * w1;
    }
    __syncthreads();
  }
  const int e0 = te * 2;
#pragma unroll
  for (int ei = 0; ei < 2; ++ei) {
    double bias = (double)gb[e0 + ei];
    float4 r;
    r.x = (float)(acc[0][ei] + bias);
    r.y = (float)(acc[1][ei] + bias);
    r.z = (float)(acc[2][ei] + bias);
    r.w = (float)(acc[3][ei] + bias);
    *(float4*)&logitsT[((size_t)b * NE + e0 + ei) * NS + s0 + tm * 4] = r;
  }
}

// ---------------------------------------------------------------------------
// Kernel 2: per (b,e): softmax denom over S + top-8 by logit (ties -> lower
// index, matching jax.lax.top_k). One wave per (b,e).
// ---------------------------------------------------------------------------
__global__ __launch_bounds__(64) void k_topk(const float* __restrict__ logitsT,
                                             float* __restrict__ tval,
                                             int* __restrict__ tidx) {
  const int be = blockIdx.x;
  const float* row = logitsT + (size_t)be * NS;
  const int lane = threadIdx.x;

  float p8[8]; int i8[8];
#pragma unroll
  for (int j = 0; j < 8; ++j) { p8[j] = -INFINITY; i8[j] = 0x7fffffff; }
  float mx = -INFINITY;
  for (int s = lane; s < NS; s += 64) {
    float l = row[s];
    mx = fmaxf(mx, l);
    if (l > p8[0] || (l == p8[0] && s < i8[0])) {
      int pos = 0;
#pragma unroll
      for (int j = 1; j < 8; ++j) {
        if (l > p8[j] || (l == p8[j] && s < i8[j])) {
          p8[j - 1] = p8[j]; i8[j - 1] = i8[j]; pos = j;
        } else break;
      }
      p8[pos] = l; i8[pos] = s;
    }
  }
#pragma unroll
  for (int off = 32; off; off >>= 1) mx = fmaxf(mx, __shfl_xor(mx, off));
  double sum = 0.0;
  for (int s = lane; s < NS; s += 64) sum += (double)expf(row[s] - mx);
#pragma unroll
  for (int off = 32; off; off >>= 1) sum += __shfl_xor(sum, off);
  const double inv = 1.0 / sum;

  int ptr = 7;
  for (int r = 0; r < 8; ++r) {
    float bp = (ptr >= 0) ? p8[ptr] : -INFINITY;
    int   bi = (ptr >= 0) ? i8[ptr] : 0x7fffffff;
    int   bl = lane;
#pragma unroll
    for (int off = 1; off < 64; off <<= 1) {
      float op = __shfl_xor(bp, off);
      int   oi = __shfl_xor(bi, off);
      int   ol = __shfl_xor(bl, off);
      if (op > bp || (op == bp && oi < bi)) { bp = op; bi = oi; bl = ol; }
    }
    if (lane == 0) {
      tval[be * 8 + r] = (float)((double)expf(bp - mx) * inv);
      tidx[be * 8 + r] = bi;
    }
    if (lane == bl) ptr--;
  }
}

// ---------------------------------------------------------------------------
// Kernel 3: mux/merge  merged[e][b][d] = sum_k val_k * x[b][idx_k][d],
// emitted directly as split-bf16 (hi/lo) in the FFN's A layout [e][m=b][k=d].
// ---------------------------------------------------------------------------
__global__ __launch_bounds__(256) void k_merge(const float* __restrict__ x,
                                               const float* __restrict__ tval,
                                               const int* __restrict__ tidx,
                                               unsigned short* __restrict__ Ah,
                                               unsigned short* __restrict__ Al) {
  const int be = blockIdx.x;
  const int b  = be >> 5;
  const int e  = be & 31;
  const int t  = threadIdx.x;
  float4 acc = {0.f, 0.f, 0.f, 0.f};
#pragma unroll
  for (int k = 0; k < 8; ++k) {
    float v = tval[be * 8 + k];
    int   s = tidx[be * 8 + k];
    float4 xv = *(const float4*)&x[((size_t)b * NS + s) * ND + t * 4];
    acc.x += v * xv.x; acc.y += v * xv.y; acc.z += v * xv.z; acc.w += v * xv.w;
  }
  unsigned short h[4], lo[4];
  split_bf16(acc.x, h[0], lo[0]); split_bf16(acc.y, h[1], lo[1]);
  split_bf16(acc.z, h[2], lo[2]); split_bf16(acc.w, h[3], lo[3]);
  const size_t o = ((size_t)e * 64 + b) * ND + t * 4;
  *(ushort4*)&Ah[o] = make_ushort4(h[0], h[1], h[2], h[3]);
  *(ushort4*)&Al[o] = make_ushort4(lo[0], lo[1], lo[2], lo[3]);
}

// ---------------------------------------------------------------------------
// Kernels 4/5: per-expert FFN GEMM via split-bf16 MFMA (16x16x32).
// Out = A[64,K] . W[K,N] (+bias row K). 3-term split: AhWh + AlWh + AhWl.
// Tile: M=64 x BN=128, BK=64, 4 waves (2x2), LDS 48KB (A 16K + W 32K),
// XOR-swizzled [row][k] bf16 layouts so ds_read_b128 is ~conflict-free.
// W streamed fp32 from HBM (n-interleaved dword loads -> bank-spread
// transposed LDS writes), converted to hi/lo bf16 in-register.
// ---------------------------------------------------------------------------
template <int K, int N, bool GELU>
__global__ __launch_bounds__(256) void k_ffn_mfma(const unsigned short* __restrict__ Agh,
                                                  const unsigned short* __restrict__ Agl,
                                                  const float* __restrict__ W,
                                                  unsigned short* __restrict__ Oh,
                                                  unsigned short* __restrict__ Ol,
                                                  float* __restrict__ Of) {
  const int e  = blockIdx.y;
  const int n0 = blockIdx.x * 128;
  const int t  = threadIdx.x;
  const int l  = t & 63;
  const int w  = t >> 6;
  const int wr = w >> 1, wc = w & 1;

  __shared__ short Ah[64 * 64], Al[64 * 64];    // [m][k^swz]  8KB each
  __shared__ short Bh[128 * 64], Bl[128 * 64];  // [n][k^swz] 16KB each

  const float* Wbase = W + (size_t)e * (K + 1) * N;

  f32x4 acc[2][4] = {};
  const int am = t >> 2;         // A staging: row
  const int ac = (t & 3) * 2;    // A staging: chunk pair (8 elems each)
  const int nb = t & 31;         // W staging: n id
  const int kb = t >> 5;         // W staging: k-block of 8 rows

  for (int k0 = 0; k0 < K; k0 += 64) {
    // stage A (already split bf16 in global)
    {
      const size_t g = ((size_t)e * 64 + am) * K + k0;
#pragma unroll
      for (int q = 0; q < 2; ++q) {
        const int ks  = (ac + q) * 8;
        const int off = am * 64 + (ks ^ ((am & 7) * 8));
        *(uint4*)&Ah[off] = *(const uint4*)&Agh[g + ks];
        *(uint4*)&Al[off] = *(const uint4*)&Agl[g + ks];
      }
    }
    // stage W: fp32 -> hi/lo bf16, transpose to [n][k]
    {
      const float* Wg = Wbase + (size_t)(k0 + kb * 8) * N + n0 + nb;
      float v[8][4];
#pragma unroll
      for (int i = 0; i < 8; ++i)
#pragma unroll
        for (int j = 0; j < 4; ++j) v[i][j] = Wg[(size_t)i * N + 32 * j];
#pragma unroll
      for (int j = 0; j < 4; ++j) {
        const int n = nb + 32 * j;
        unsigned short h8[8], l8[8];
#pragma unroll
        for (int i = 0; i < 8; ++i) split_bf16(v[i][j], h8[i], l8[i]);
        const int off = n * 64 + ((kb * 8) ^ ((n & 7) * 8));
        *(uint4*)&Bh[off] = *(const uint4*)h8;
        *(uint4*)&Bl[off] = *(const uint4*)l8;
      }
    }
    __syncthreads();
#pragma unroll
    for (int ks = 0; ks < 2; ++ks) {
      const int koff = ks * 32 + (l >> 4) * 8;
      bf16x8 ah[2], alo[2], bh[4], blo[4];
#pragma unroll
      for (int mf = 0; mf < 2; ++mf) {
        const int r   = wr * 32 + mf * 16 + (l & 15);
        const int off = r * 64 + (koff ^ ((r & 7) * 8));
        ah[mf]  = *(const bf16x8*)&Ah[off];
        alo[mf] = *(const bf16x8*)&Al[off];
      }
#pragma unroll
      for (int nf = 0; nf < 4; ++nf) {
        const int n   = wc * 64 + nf * 16 + (l & 15);
        const int off = n * 64 + (koff ^ ((n & 7) * 8));
        bh[nf]  = *(const bf16x8*)&Bh[off];
        blo[nf] = *(const bf16x8*)&Bl[off];
      }
#pragma unroll
      for (int mf = 0; mf < 2; ++mf)
#pragma unroll
        for (int nf = 0; nf < 4; ++nf) {
          acc[mf][nf] = __builtin_amdgcn_mfma_f32_16x16x32_bf16(ah[mf],  bh[nf],  acc[mf][nf], 0, 0, 0);
          acc[mf][nf] = __builtin_amdgcn_mfma_f32_16x16x32_bf16(alo[mf], bh[nf],  acc[mf][nf], 0, 0, 0);
          acc[mf][nf] = __builtin_amdgcn_mfma_f32_16x16x32_bf16(ah[mf],  blo[nf], acc[mf][nf], 0, 0, 0);
        }
    }
    __syncthreads();
  }
  // epilogue: +bias, optional exact GELU, store
#pragma unroll
  for (int nf = 0; nf < 4; ++nf) {
    const int   c    = n0 + wc * 64 + nf * 16 + (l & 15);
    const float bias = Wbase[(size_t)K * N + c];
#pragma unroll
    for (int mf = 0; mf < 2; ++mf) {
#pragma unroll
      for (int j = 0; j < 4; ++j) {
        const int m = wr * 32 + mf * 16 + (l >> 4) * 4 + j;
        float v = acc[mf][nf][j] + bias;
        if (GELU) {
          v = 0.5f * v * (1.0f + erff(v * 0.70710678118654752440f));
          unsigned short h, lo;
          split_bf16(v, h, lo);
          Oh[((size_t)e * 64 + m) * N + c] = h;
          Ol[((size_t)e * 64 + m) * N + c] = lo;
        } else {
          Of[((size_t)m * NE + e) * N + c] = v;
        }
      }
    }
  }
}

// ---------------------------------------------------------------------------
// Kernel 6: demux/scatter (deterministic, atomic-free; zero-fills unpicked
// tokens). One block per (b, token).
// ---------------------------------------------------------------------------
__global__ __launch_bounds__(256) void k_scatter(const float* __restrict__ Obuf,
                                                 const float* __restrict__ tval,
                                                 const int* __restrict__ tidx,
                                                 float* __restrict__ out) {
  const int s = blockIdx.x;
  const int b = blockIdx.y;
  const int t = threadIdx.x;
  __shared__ unsigned long long masks[4];

  const int myIdx = tidx[b * 256 + t];  // slot t = e*8 + k
  unsigned long long m = __ballot(myIdx == s);
  if ((t & 63) == 0) masks[t >> 6] = m;
  __syncthreads();

  float4 acc = {0.f, 0.f, 0.f, 0.f};
#pragma unroll
  for (int w = 0; w < 4; ++w) {
    unsigned long long mm = masks[w];
    while (mm) {
      int bit = __ffsll(mm) - 1;
      mm &= mm - 1;
      int r = w * 64 + bit;             // r = e*8 + k
      float v = tval[b * 256 + r];
      const float4 ov = *(const float4*)&Obuf[((size_t)b * NE + (r >> 3)) * ND + t * 4];
      acc.x += v * ov.x; acc.y += v * ov.y; acc.z += v * ov.z; acc.w += v * ov.w;
    }
  }
  *(float4*)&out[((size_t)b * NS + s) * ND + t * 4] = acc;
}

// ---------------------------------------------------------------------------
extern "C" void kernel_launch(void* const* d_in, const int* in_sizes, int n_in,
                              void* d_out, int out_size, void* d_ws, size_t ws_size,
                              hipStream_t stream) {
  const float* x  = (const float*)d_in[0];
  const float* gw = (const float*)d_in[1];
  const float* gb = (const float*)d_in[2];
  const float* w1 = (const float*)d_in[3];
  const float* w2 = (const float*)d_in[4];
  float* out = (float*)d_out;

  // workspace layout (bytes): 67.24 MB total
  char* ws = (char*)d_ws;
  float* logitsT      = (float*)ws;                          // 16,777,216 B
  float* tval         = (float*)(ws + 16777216);             //     65,536 B
  int*   tidx         = (int*)  (ws + 16842752);             //     65,536 B
  unsigned short* A1h = (unsigned short*)(ws + 16908288);    //  4,194,304 B
  unsigned short* A1l = (unsigned short*)(ws + 21102592);    //  4,194,304 B
  unsigned short* Hh  = (unsigned short*)(ws + 25296896);    // 16,777,216 B
  unsigned short* Hl  = (unsigned short*)(ws + 42074112);    // 16,777,216 B
  float* Obuf         = (float*)(ws + 58851328);             //  8,388,608 B

  k_gate<<<dim3(NS / 64, NB), 256, 0, stream>>>(x, gw, gb, logitsT);
  k_topk<<<NB * NE, 64, 0, stream>>>(logitsT, tval, tidx);
  k_merge<<<NB * NE, 256, 0, stream>>>(x, tval, tidx, A1h, A1l);
  k_ffn_mfma<ND, NH, true ><<<dim3(NH / 128, NE), 256, 0, stream>>>(A1h, A1l, w1, Hh, Hl, nullptr);
  k_ffn_mfma<NH, ND, false><<<dim3(ND / 128, NE), 256, 0, stream>>>(Hh, Hl, w2, nullptr, nullptr, Obuf);
  k_scatter<<<dim3(NS, NB), 256, 0, stream>>>(Obuf, tval, tidx, out);
}